// Round 10
// baseline (254.203 us; speedup 1.0000x reference)
//
#include <hip/hip_runtime.h>
#include <hip/hip_fp16.h>
#include <math.h>

// Problem constants (from reference setup_inputs)
constexpr int N    = 50000;   // nodes
constexpr int E    = 800000;  // edges
constexpr int CIN  = 100;     // input channels
constexpr int CH   = 128;     // hidden channels
constexpr int COUT = 47;      // output channels
constexpr int NOUT = 25000;   // original_size (rows emitted)
constexpr int CP   = 48;      // COUT padded (storage stride)
constexpr int NB   = (N + 255) / 256;        // 196 scan blocks
constexpr int TN   = 128;                    // gemm tile nodes
constexpr int NT   = (N + TN - 1) / TN;      // 391 gemm blocks

// MFMA split-bf16 constants
constexpr int HS  = 136;  // h LDS row stride (ushort) = 272 B (16B-aligned rows)
constexpr int W1K = 256;  // w1T row length (k): [agg1 0..99|0 | x 0..99|0]
constexpr int W2K = 128;  // w2T row length (k)
constexpr int A1S = 256;  // a1x row stride (halves) — mirrors w1T k-layout

// R20 XCD-range-partitioned CSR constants
constexpr int RNG = N / 8;                     // 6250 dst per range (exact)
constexpr int ECH = 2048;                      // edges per chunk (256 thr x 8)
constexpr int NCH = (E + ECH - 1) / ECH;       // 391 chunks
constexpr int HB8 = 8 * NCH;                   // 3128 range-partitioned blocks

// pre_kernel block partition
constexpr int CB = (N * 32) / 256;             // 6250 convert blocks (32 u2/row)
constexpr int PB = 193;                        // prep blocks (49280 elems)

typedef float f32x4 __attribute__((ext_vector_type(4)));
typedef short v8s  __attribute__((ext_vector_type(8)));   // 8 bf16 (4 VGPRs)

// split fp32 -> truncated bf16 hi + bf16(residual) lo. For fp16 inputs the
// split is EXACT (11-bit mantissa = 8 hi + <=3 lo); dropping lo*lo in the
// 3-term MFMA leaves ~2^-16 rel error per product.
__device__ __forceinline__ void bsplit(float f, ushort& h, ushort& l) {
    uint u = __float_as_uint(f);
    h = (ushort)(u >> 16);
    float fh = __uint_as_float(u & 0xffff0000u);
    l = (ushort)(__float_as_uint(f - fh) >> 16);
}

// unpack 8 fp16 (one 16B vector) -> bf16 hi/lo MFMA fragments
__device__ __forceinline__ void unpack8(uint4 v, v8s& ah, v8s& al) {
    union { uint4 u; __half2 h[4]; } V; V.u = v;
    ushort hh[8], ll[8];
    #pragma unroll
    for (int p = 0; p < 4; ++p) {
        float2 f = __half22float2(V.h[p]);
        bsplit(f.x, hh[2 * p],     ll[2 * p]);
        bsplit(f.y, hh[2 * p + 1], ll[2 * p + 1]);
    }
    ah = v8s{(short)hh[0], (short)hh[1], (short)hh[2], (short)hh[3],
             (short)hh[4], (short)hh[5], (short)hh[6], (short)hh[7]};
    al = v8s{(short)ll[0], (short)ll[1], (short)ll[2], (short)ll[3],
             (short)ll[4], (short)ll[5], (short)ll[6], (short)ll[7]};
}

// ---------------------------------------------------------------------------
// pre_kernel: fused {hist | convert_x | prep_w}.
// R20 hist: range-partitioned, returnless atomics. Blocks in groups of 8:
// bid%8 = dst-range r; round-robin dispatch pins range r to XCD r, so cnt
// lines never bounce between L2s, and no wave waits on an atomic return
// (rank eliminated). dst re-read 8x but L2-resident (3.2 MB).
__global__ __launch_bounds__(256) void pre_kernel(
        const int* __restrict__ dst, int* __restrict__ cnt,
        const float* __restrict__ x, __half* __restrict__ x16,
        __half* __restrict__ a1x,
        const float* __restrict__ w1l, const float* __restrict__ w1r,
        const float* __restrict__ w2l, const float* __restrict__ w2r,
        const float* __restrict__ b2l,
        ushort* __restrict__ w1T, ushort* __restrict__ w2T,
        float* __restrict__ b2cat) {
    int bid = blockIdx.x, t = threadIdx.x;
    if (bid < HB8) {
        int r = bid & 7, c = bid >> 3;
        int e0 = c * ECH + t * 8;          // E%8==0: group fully in or out
        if (e0 < E) {
            int4 d0 = *(const int4*)(dst + e0);
            int4 d1 = *(const int4*)(dst + e0 + 4);
            int lo = r * RNG;
            int dd[8] = {d0.x, d0.y, d0.z, d0.w, d1.x, d1.y, d1.z, d1.w};
            #pragma unroll
            for (int k = 0; k < 8; ++k)
                if ((unsigned)(dd[k] - lo) < (unsigned)RNG)
                    atomicAdd(&cnt[dd[k]], 1);
        }
    } else if (bid < HB8 + CB) {
        // x -> fp16: packed x16[N][100] (gather payload) AND the x-section of
        // a1x[N][256] halves 128..255 (cols >=100 zeroed).
        int j = (bid - HB8) * 256 + t;     // j over N*32 u2 slots
        int row = j >> 5, s = j & 31;
        uint2 u = make_uint2(0u, 0u);
        if (s < 25) {
            float4 v = ((const float4*)x)[row * 25 + s];
            __half2 h0 = __floats2half2_rn(v.x, v.y);
            __half2 h1 = __floats2half2_rn(v.z, v.w);
            union { __half2 h[2]; uint2 u; } U;
            U.h[0] = h0; U.h[1] = h1;
            u = U.u;
            ((uint2*)x16)[row * 25 + s] = u;
        }
        ((uint2*)a1x)[(size_t)row * 64 + 32 + s] = u;
    } else {
        // weight transpose + bf16 hi/lo split
        // w1T: [n<128][k<256]: k<100 -> w1l[k][n]; 128<=k<228 -> w1r[k-128][n]
        // w2T: [n<128][k<128]: n<47 -> w2l[k][n]; 64<=n<111 -> w2r[k][n-64]
        int i = (bid - HB8 - CB) * 256 + t;
        if (i < 128 * W1K) {
            int n = i >> 8, k = i & 255;
            float v = 0.0f;
            if (k < 100)                    v = w1l[(size_t)k * CH + n];
            else if (k >= 128 && k < 228)   v = w1r[(size_t)(k - 128) * CH + n];
            ushort h, l; bsplit(v, h, l);
            w1T[i] = h; w1T[128 * W1K + i] = l;
        } else if (i < 128 * W1K + 128 * W2K) {
            int j2 = i - 128 * W1K;
            int n = j2 >> 7, k = j2 & 127;
            float v = 0.0f;
            if (n < COUT)                      v = w2l[(size_t)k * COUT + n];
            else if (n >= 64 && n < 64 + COUT) v = w2r[(size_t)k * COUT + (n - 64)];
            ushort h, l; bsplit(v, h, l);
            w2T[j2] = h; w2T[128 * W2K + j2] = l;
        } else {
            int j2 = i - (128 * W1K + 128 * W2K);
            if (j2 < 128) b2cat[j2] = (j2 >= 64 && j2 < 64 + COUT) ? b2l[j2 - 64] : 0.0f;
        }
    }
}

// CSR stage 2a: per-block exclusive scan of cnt
__global__ __launch_bounds__(256) void scan_blocks(const int* __restrict__ cnt,
        int* __restrict__ row_ptr, int* __restrict__ blkSum) {
    __shared__ int s[256];
    int t = threadIdx.x;
    int i = blockIdx.x * 256 + t;
    int v = (i < N) ? cnt[i] : 0;
    s[t] = v;
    __syncthreads();
    for (int off = 1; off < 256; off <<= 1) {
        int a = s[t];
        int u = (t >= off) ? s[t - off] : 0;
        __syncthreads();
        s[t] = a + u;
        __syncthreads();
    }
    if (i < N) row_ptr[i] = s[t] - v;
    if (t == 255) blkSum[blockIdx.x] = s[255];
}

// CSR stage 2b: reduce blkSum prefix, apply offset; also init cursor.
__global__ __launch_bounds__(256) void scan_apply(int* __restrict__ row_ptr,
        int* __restrict__ cursor, const int* __restrict__ blkSum) {
    __shared__ int s[256];
    int t = threadIdx.x, bid = blockIdx.x;
    int a = 0;
    for (int j = t; j < bid; j += 256) a += blkSum[j];
    s[t] = a;
    __syncthreads();
    for (int off = 128; off > 0; off >>= 1) {
        if (t < off) s[t] += s[t + off];
        __syncthreads();
    }
    int offset = s[0];
    int i = bid * 256 + t;
    if (i < N) {
        int v = row_ptr[i] + offset;
        row_ptr[i] = v;
        cursor[i]  = v;
        if (i == N - 1) row_ptr[N] = E;
    }
}

// CSR stage 3 (R20): range-partitioned cursor-atomic fill. Same bid%8 = range
// trick: cursor lines stay XCD-local (atomic-with-return ~200cyc not ~900),
// 8 independent edge chains per thread (MLP-8). src/dst re-reads are
// L2-resident. col writes scattered (unavoidable).
__global__ void fill_kernel(const int* __restrict__ src, const int* __restrict__ dst,
        int* __restrict__ cursor, int* __restrict__ col) {
    int r = blockIdx.x & 7, c = blockIdx.x >> 3;
    int e0 = c * ECH + threadIdx.x * 8;
    if (e0 >= E) return;
    int4 d0 = *(const int4*)(dst + e0);
    int4 d1 = *(const int4*)(dst + e0 + 4);
    int4 s0 = *(const int4*)(src + e0);
    int4 s1 = *(const int4*)(src + e0 + 4);
    int lo = r * RNG;
    int dd[8] = {d0.x, d0.y, d0.z, d0.w, d1.x, d1.y, d1.z, d1.w};
    int ss[8] = {s0.x, s0.y, s0.z, s0.w, s1.x, s1.y, s1.z, s1.w};
    #pragma unroll
    for (int k = 0; k < 8; ++k) {
        if ((unsigned)(dd[k] - lo) < (unsigned)RNG) {
            int p = atomicAdd(&cursor[dd[k]], 1);
            col[p] = ss[k];
        }
    }
}

// ---------------------------------------------------------------------------
// gather1 (standalone — 24 VGPR, high occupancy; R18 lesson): fp16 source
// rows (200B). One node per wave; two 32-lane halves take even/odd edges,
// unroll-4 per half; fp32 accumulation; cross-half __shfl_xor(..,32).
// Output: agg-section of a1x (halves 0..127; li>=25 lanes write the zero pad).
__global__ __launch_bounds__(256) void gather1_kernel(const __half* __restrict__ x16,
        const int* __restrict__ row_ptr, const int* __restrict__ col,
        __half* __restrict__ a1x) {
    int t = threadIdx.x;
    int n = blockIdx.x * 4 + (t >> 6);     // node per wave
    int l = t & 63, half = l >> 5, li = l & 31;
    int b = row_ptr[n], e = row_ptr[n + 1];
    float inv = 1.0f / (float)max(e - b, 1);
    const uint2* xb = (const uint2*)x16;   // row = 25 uint2 (4 halves each)
    bool act = li < 25;
    float4 s0 = make_float4(0.f, 0.f, 0.f, 0.f);
    float4 s1 = make_float4(0.f, 0.f, 0.f, 0.f);
    float4 s2 = make_float4(0.f, 0.f, 0.f, 0.f);
    float4 s3 = make_float4(0.f, 0.f, 0.f, 0.f);
    union { uint2 u; __half2 h[2]; } U0, U1, U2, U3;
    int j = b + half;
    for (; j + 6 < e; j += 8) {
        int c0 = col[j], c1 = col[j + 2], c2 = col[j + 4], c3 = col[j + 6];
        if (act) {
            U0.u = xb[(size_t)c0 * 25 + li];
            U1.u = xb[(size_t)c1 * 25 + li];
            U2.u = xb[(size_t)c2 * 25 + li];
            U3.u = xb[(size_t)c3 * 25 + li];
            float2 f0a = __half22float2(U0.h[0]), f0b = __half22float2(U0.h[1]);
            float2 f1a = __half22float2(U1.h[0]), f1b = __half22float2(U1.h[1]);
            float2 f2a = __half22float2(U2.h[0]), f2b = __half22float2(U2.h[1]);
            float2 f3a = __half22float2(U3.h[0]), f3b = __half22float2(U3.h[1]);
            s0.x += f0a.x; s0.y += f0a.y; s0.z += f0b.x; s0.w += f0b.y;
            s1.x += f1a.x; s1.y += f1a.y; s1.z += f1b.x; s1.w += f1b.y;
            s2.x += f2a.x; s2.y += f2a.y; s2.z += f2b.x; s2.w += f2b.y;
            s3.x += f3a.x; s3.y += f3a.y; s3.z += f3b.x; s3.w += f3b.y;
        }
    }
    for (; j < e; j += 2) {
        int c0 = col[j];
        if (act) {
            U0.u = xb[(size_t)c0 * 25 + li];
            float2 f0a = __half22float2(U0.h[0]), f0b = __half22float2(U0.h[1]);
            s0.x += f0a.x; s0.y += f0a.y; s0.z += f0b.x; s0.w += f0b.y;
        }
    }
    float4 s = make_float4(s0.x + s1.x + s2.x + s3.x,
                           s0.y + s1.y + s2.y + s3.y,
                           s0.z + s1.z + s2.z + s3.z,
                           s0.w + s1.w + s2.w + s3.w);
    s.x += __shfl_xor(s.x, 32, 64);
    s.y += __shfl_xor(s.y, 32, 64);
    s.z += __shfl_xor(s.z, 32, 64);
    s.w += __shfl_xor(s.w, 32, 64);
    if (half == 0) {                      // li>=25 lanes hold zeros -> pad
        __half2 p0 = __floats2half2_rn(s.x * inv, s.y * inv);
        __half2 p1 = __floats2half2_rn(s.z * inv, s.w * inv);
        union { __half2 h[2]; uint2 u; } P;
        P.h[0] = p0; P.h[1] = p1;
        ((uint2*)a1x)[(size_t)n * 64 + li] = P.u;
    }
}

// ---------------------------------------------------------------------------
// fused gemm (R19 structure): stage-1 is a single K=256 LDS-FREE direct-load
// GEMM — A-frags (16B = 8 fp16) read straight from a1x[N][256] (= [agg1|0|x|0],
// mirroring w1T's k-layout), bsplit in-register. No staging, no stage-1
// barriers. h spills to LDS as bf16 hi/lo planes (stride 272B, ONE barrier),
// then stage-2 = h @ w2T^T. 3-term hh+hl+lh in fp32.
// LDS = 69632 B (H planes only) -> 2 blocks/CU.
__global__ __launch_bounds__(256) void fused_gemm(
        const __half* __restrict__ a1x,
        const ushort* __restrict__ w1T, const float* __restrict__ b1l,
        const ushort* __restrict__ w2T, const float* __restrict__ b2cat,
        __half* __restrict__ gsrc16, float* __restrict__ gself) {
    __shared__ __align__(16) uint lds_u[17408];   // 69632 B
    ushort* Hh = (ushort*)lds_u;                  // [128][HS]  (h hi)
    ushort* Hl = Hh + 128 * HS;                   // [128][HS]  (h lo)

    int t = threadIdx.x;
    int lane = t & 63;
    int wv = __builtin_amdgcn_readfirstlane(t >> 6);
    int nh = wv & 1, chh = wv >> 1;
    int l15 = lane & 15, lg = lane >> 4;
    int base = blockIdx.x * TN;

    const ushort* w1Th = w1T;
    const ushort* w1Tl = w1T + 128 * W1K;
    const ushort* w2Th = w2T;
    const ushort* w2Tl = w2T + 128 * W2K;

    f32x4 acc[4][4];
    #pragma unroll
    for (int nt = 0; nt < 4; ++nt) {
        float bv = b1l[chh * 64 + nt * 16 + l15];
        #pragma unroll
        for (int mt = 0; mt < 4; ++mt)
            acc[mt][nt] = f32x4{bv, bv, bv, bv};
    }

    // ---- stage 1: K=256, direct loads, no LDS, no barriers
    #pragma unroll 2
    for (int ks = 0; ks < 8; ++ks) {
        int k0 = ks * 32 + lg * 8;
        v8s ahf[4], alf[4];
        #pragma unroll
        for (int mt = 0; mt < 4; ++mt) {
            int row = base + nh * 64 + mt * 16 + l15;
            int rr = row < N ? row : N - 1;       // clamp loads; stores guarded
            uint4 v = *(const uint4*)(a1x + (size_t)rr * A1S + k0);
            unpack8(v, ahf[mt], alf[mt]);
        }
        #pragma unroll
        for (int nt = 0; nt < 4; ++nt) {
            int n = chh * 64 + nt * 16 + l15;
            v8s bhf = *(const v8s*)(w1Th + (size_t)n * W1K + k0);
            v8s blf = *(const v8s*)(w1Tl + (size_t)n * W1K + k0);
            #pragma unroll
            for (int mt = 0; mt < 4; ++mt) {
                acc[mt][nt] = __builtin_amdgcn_mfma_f32_16x16x32_bf16(
                    ahf[mt], bhf, acc[mt][nt], 0, 0, 0);
                acc[mt][nt] = __builtin_amdgcn_mfma_f32_16x16x32_bf16(
                    alf[mt], bhf, acc[mt][nt], 0, 0, 0);
                acc[mt][nt] = __builtin_amdgcn_mfma_f32_16x16x32_bf16(
                    ahf[mt], blf, acc[mt][nt], 0, 0, 0);
            }
        }
    }

    // ---- spill h tile to LDS as bf16 hi/lo planes
    #pragma unroll
    for (int mt = 0; mt < 4; ++mt) {
        #pragma unroll
        for (int nt = 0; nt < 4; ++nt) {
            int ch = chh * 64 + nt * 16 + l15;
            #pragma unroll
            for (int r = 0; r < 4; ++r) {
                int node = nh * 64 + mt * 16 + lg * 4 + r;
                ushort h, l; bsplit(acc[mt][nt][r], h, l);
                Hh[node * HS + ch] = h;
                Hl[node * HS + ch] = l;
            }
        }
    }
    __syncthreads();

    // ---- stage 2: [gsrc|gself] = h @ w2T^T (+ b2cat)
    bool skip = (chh == 1) && (base >= NOUT);
    if (!skip) {
        #pragma unroll
        for (int nt = 0; nt < 4; ++nt) {
            float bv = b2cat[chh * 64 + nt * 16 + l15];
            #pragma unroll
            for (int mt = 0; mt < 4; ++mt)
                acc[mt][nt] = f32x4{bv, bv, bv, bv};
        }
        #pragma unroll
        for (int ks = 0; ks < 4; ++ks) {          // K=128, 4 k-steps of 32
            v8s ahf[4], alf[4];
            #pragma unroll
            for (int mt = 0; mt < 4; ++mt) {
                int node = nh * 64 + mt * 16 + l15;
                int ko = ks * 32 + lg * 8;
                ahf[mt] = *(const v8s*)(Hh + node * HS + ko);
                alf[mt] = *(const v8s*)(Hl + node * HS + ko);
            }
            int kg = ks * 32 + lg * 8;
            #pragma unroll
            for (int nt = 0; nt < 4; ++nt) {
                int n = chh * 64 + nt * 16 + l15;
                v8s bhf = *(const v8s*)(w2Th + (size_t)n * W2K + kg);
                v8s blf = *(const v8s*)(w2Tl + (size_t)n * W2K + kg);
                #pragma unroll
                for (int mt = 0; mt < 4; ++mt) {
                    acc[mt][nt] = __builtin_amdgcn_mfma_f32_16x16x32_bf16(
                        ahf[mt], bhf, acc[mt][nt], 0, 0, 0);
                    acc[mt][nt] = __builtin_amdgcn_mfma_f32_16x16x32_bf16(
                        alf[mt], bhf, acc[mt][nt], 0, 0, 0);
                    acc[mt][nt] = __builtin_amdgcn_mfma_f32_16x16x32_bf16(
                        ahf[mt], blf, acc[mt][nt], 0, 0, 0);
                }
            }
        }
        int lim = chh ? NOUT : N;
        #pragma unroll
        for (int nt = 0; nt < 3; ++nt) {          // cols 0..47 only
            int colc = nt * 16 + l15;
            #pragma unroll
            for (int mt = 0; mt < 4; ++mt) {
                #pragma unroll
                for (int r = 0; r < 4; ++r) {
                    int node = base + nh * 64 + mt * 16 + lg * 4 + r;
                    if (node < lim) {
                        if (chh) gself[(size_t)node * CP + colc] = acc[mt][nt][r];
                        else gsrc16[(size_t)node * CP + colc] =
                                 __float2half(acc[mt][nt][r]);
                    }
                }
            }
        }
    }
}

// ---------------------------------------------------------------------------
// final: 4 nodes per 256-block (one per wave), unroll-4 fp16 gsrc gather.
// out nt store is safe: out is never read on-device.
__global__ __launch_bounds__(256) void final_kernel(const __half* __restrict__ gsrc16,
        const float* __restrict__ gself, const int* __restrict__ row_ptr,
        const int* __restrict__ col, float* __restrict__ out) {
    int t = threadIdx.x;
    int n = blockIdx.x * 4 + (t >> 6);
    int c = t & 63;
    int b = row_ptr[n], e = row_ptr[n + 1];
    float inv = 1.0f / (float)max(e - b, 1);
    float a0 = 0.f, a1 = 0.f, a2 = 0.f, a3 = 0.f;
    if (c < CP) {
        int j = b;
        for (; j + 3 < e; j += 4) {
            a0 += __half2float(gsrc16[(size_t)col[j]     * CP + c]);
            a1 += __half2float(gsrc16[(size_t)col[j + 1] * CP + c]);
            a2 += __half2float(gsrc16[(size_t)col[j + 2] * CP + c]);
            a3 += __half2float(gsrc16[(size_t)col[j + 3] * CP + c]);
        }
        for (; j < e; ++j) a0 += __half2float(gsrc16[(size_t)col[j] * CP + c]);
    }
    float val = (c < COUT)
        ? (((a0 + a1) + (a2 + a3)) * inv + gself[(size_t)n * CP + c]) : -INFINITY;
    float m = val;
    #pragma unroll
    for (int off = 32; off > 0; off >>= 1) m = fmaxf(m, __shfl_xor(m, off, 64));
    float ex = (c < COUT) ? expf(val - m) : 0.f;
    float ssum = ex;
    #pragma unroll
    for (int off = 32; off > 0; off >>= 1) ssum += __shfl_xor(ssum, off, 64);
    if (c < COUT)
        __builtin_nontemporal_store(val - m - logf(ssum),
                                    out + (size_t)n * COUT + c);
}

// ---------------------------------------------------------------------------
extern "C" void kernel_launch(void* const* d_in, const int* in_sizes, int n_in,
                              void* d_out, int out_size, void* d_ws, size_t ws_size,
                              hipStream_t stream) {
    const float* x   = (const float*)d_in[0];
    const int*   ei  = (const int*)d_in[1];   // [2, E]: row 0 = src, row 1 = dst
    const int*   src = ei;
    const int*   dst = ei + E;
    const float* w1l = (const float*)d_in[3];
    const float* b1l = (const float*)d_in[4];
    const float* w1r = (const float*)d_in[5];
    const float* w2l = (const float*)d_in[6];
    const float* b2l = (const float*)d_in[7];
    const float* w2r = (const float*)d_in[8];
    float* out = (float*)d_out;

    // ws: ints [cnt N | row_ptr N+1 | cursor N | blkSum NB | col E]
    // floats [gself NOUT*CP | b2cat 128]
    // halves [gsrc16 N*CP | x16 N*CIN | a1x N*256]
    // ushorts [w1T hi+lo 2*128*256 | w2T hi+lo 2*128*128]
    int* cnt     = (int*)d_ws;
    int* row_ptr = cnt + N;
    int* cursor  = row_ptr + N + 1;
    int* blkSum  = cursor + N;
    int* col     = blkSum + NB;
    size_t intWords = (size_t)N + (N + 1) + N + NB + E;
    intWords = (intWords + 3) & ~(size_t)3;
    float* gself  = (float*)d_ws + intWords;
    float* b2cat  = gself + (size_t)NOUT * CP;
    __half* gsrc16 = (__half*)(b2cat + 128);
    __half* x16    = gsrc16 + (size_t)N * CP;
    __half* a1x    = x16 + (size_t)N * CIN;       // 16B-aligned (counts %8==0)
    ushort* w1T   = (ushort*)(a1x + (size_t)N * A1S);
    ushort* w2T   = w1T + 2 * 128 * W1K;
    // total ws ~49.5 MB (< 58.6 MB proven available)

    (void)hipMemsetAsync(cnt, 0, (size_t)N * sizeof(int), stream);
    pre_kernel  <<<HB8 + CB + PB, 256, 0, stream>>>(dst, cnt, x, x16, a1x,
                                                    w1l, w1r, w2l, w2r, b2l,
                                                    w1T, w2T, b2cat);
    scan_blocks <<<NB, 256, 0, stream>>>(cnt, row_ptr, blkSum);
    scan_apply  <<<NB, 256, 0, stream>>>(row_ptr, cursor, blkSum);
    fill_kernel <<<HB8, 256, 0, stream>>>(src, dst, cursor, col);
    gather1_kernel<<<N / 4, 256, 0, stream>>>(x16, row_ptr, col, a1x);
    fused_gemm  <<<NT, 256, 0, stream>>>(a1x, w1T, b1l, w2T, b2cat,
                                         gsrc16, gself);
    final_kernel<<<NOUT / 4, 256, 0, stream>>>(gsrc16, gself, row_ptr, col, out);
}

// Round 11
// 203.449 us; speedup vs baseline: 1.2495x; 1.2495x over previous
//
#include <hip/hip_runtime.h>
#include <hip/hip_fp16.h>
#include <math.h>

// Problem constants (from reference setup_inputs)
constexpr int N    = 50000;   // nodes
constexpr int E    = 800000;  // edges
constexpr int CIN  = 100;     // input channels
constexpr int CH   = 128;     // hidden channels
constexpr int COUT = 47;      // output channels
constexpr int NOUT = 25000;   // original_size (rows emitted)
constexpr int CP   = 48;      // COUT padded (storage stride)
constexpr int TN   = 128;     // gemm tile nodes
constexpr int NT   = (N + TN - 1) / TN;      // 391 gemm blocks

// MFMA split-bf16 constants
constexpr int HS  = 136;  // h LDS row stride (ushort) = 272 B (16B-aligned rows)
constexpr int W1K = 256;  // w1T row length (k): [agg1 0..99|0 | x 0..99|0]
constexpr int W2K = 128;  // w2T row length (k)
constexpr int A1S = 256;  // a1x row stride (halves) — mirrors w1T k-layout

// R21 atomic-free bucketed CSR constants
constexpr int NBUK = (N + 255) / 256;          // 196 coarse buckets (256 nodes)
constexpr int ECH  = 2048;                     // edges per chunk (256 thr x 8)
constexpr int NCH  = (E + ECH - 1) / ECH;      // 391 chunks

// pre_kernel block partition
constexpr int CB = (N * 32) / 256;             // 6250 convert blocks (32 u2/row)
constexpr int PB = 193;                        // prep blocks (49280 elems)

typedef float f32x4 __attribute__((ext_vector_type(4)));
typedef short v8s  __attribute__((ext_vector_type(8)));   // 8 bf16 (4 VGPRs)

// split fp32 -> truncated bf16 hi + bf16(residual) lo. For fp16 inputs the
// split is EXACT (11-bit mantissa = 8 hi + <=3 lo); dropping lo*lo in the
// 3-term MFMA leaves ~2^-16 rel error per product.
__device__ __forceinline__ void bsplit(float f, ushort& h, ushort& l) {
    uint u = __float_as_uint(f);
    h = (ushort)(u >> 16);
    float fh = __uint_as_float(u & 0xffff0000u);
    l = (ushort)(__float_as_uint(f - fh) >> 16);
}

// unpack 8 fp16 (one 16B vector) -> bf16 hi/lo MFMA fragments
__device__ __forceinline__ void unpack8(uint4 v, v8s& ah, v8s& al) {
    union { uint4 u; __half2 h[4]; } V; V.u = v;
    ushort hh[8], ll[8];
    #pragma unroll
    for (int p = 0; p < 4; ++p) {
        float2 f = __half22float2(V.h[p]);
        bsplit(f.x, hh[2 * p],     ll[2 * p]);
        bsplit(f.y, hh[2 * p + 1], ll[2 * p + 1]);
    }
    ah = v8s{(short)hh[0], (short)hh[1], (short)hh[2], (short)hh[3],
             (short)hh[4], (short)hh[5], (short)hh[6], (short)hh[7]};
    al = v8s{(short)ll[0], (short)ll[1], (short)ll[2], (short)ll[3],
             (short)ll[4], (short)ll[5], (short)ll[6], (short)ll[7]};
}

// ---------------------------------------------------------------------------
// pre_kernel: fused {coarse-hist (LDS, atomic-free global) | convert_x | prep_w}.
// R21: global atomics eliminated (R20 null result: XCD-locality doesn't help —
// device atomics are a fixed ~18 G/s fabric ceiling). Per-chunk 196-bin LDS
// histogram of dst>>8 -> lhist[c][b].
__global__ __launch_bounds__(256) void pre_kernel(
        const int* __restrict__ dst, int* __restrict__ lhist,
        const float* __restrict__ x, __half* __restrict__ x16,
        __half* __restrict__ a1x,
        const float* __restrict__ w1l, const float* __restrict__ w1r,
        const float* __restrict__ w2l, const float* __restrict__ w2r,
        const float* __restrict__ b2l,
        ushort* __restrict__ w1T, ushort* __restrict__ w2T,
        float* __restrict__ b2cat) {
    __shared__ int h[NBUK];
    int bid = blockIdx.x, t = threadIdx.x;
    if (bid < NCH) {
        for (int i = t; i < NBUK; i += 256) h[i] = 0;
        __syncthreads();
        int e0 = bid * ECH + t * 8;        // E%8==0: group fully in or out
        if (e0 < E) {
            int4 d0 = *(const int4*)(dst + e0);
            int4 d1 = *(const int4*)(dst + e0 + 4);
            int dd[8] = {d0.x, d0.y, d0.z, d0.w, d1.x, d1.y, d1.z, d1.w};
            #pragma unroll
            for (int k = 0; k < 8; ++k) atomicAdd(&h[dd[k] >> 8], 1);
        }
        __syncthreads();
        for (int i = t; i < NBUK; i += 256) lhist[bid * NBUK + i] = h[i];
    } else if (bid < NCH + CB) {
        // x -> fp16: packed x16[N][100] (gather payload) AND the x-section of
        // a1x[N][256] halves 128..255 (cols >=100 zeroed).
        int j = (bid - NCH) * 256 + t;     // j over N*32 u2 slots
        int row = j >> 5, s = j & 31;
        uint2 u = make_uint2(0u, 0u);
        if (s < 25) {
            float4 v = ((const float4*)x)[row * 25 + s];
            __half2 h0 = __floats2half2_rn(v.x, v.y);
            __half2 h1 = __floats2half2_rn(v.z, v.w);
            union { __half2 h[2]; uint2 u; } U;
            U.h[0] = h0; U.h[1] = h1;
            u = U.u;
            ((uint2*)x16)[row * 25 + s] = u;
        }
        ((uint2*)a1x)[(size_t)row * 64 + 32 + s] = u;
    } else {
        // weight transpose + bf16 hi/lo split
        // w1T: [n<128][k<256]: k<100 -> w1l[k][n]; 128<=k<228 -> w1r[k-128][n]
        // w2T: [n<128][k<128]: n<47 -> w2l[k][n]; 64<=n<111 -> w2r[k][n-64]
        int i = (bid - NCH - CB) * 256 + t;
        if (i < 128 * W1K) {
            int n = i >> 8, k = i & 255;
            float v = 0.0f;
            if (k < 100)                    v = w1l[(size_t)k * CH + n];
            else if (k >= 128 && k < 228)   v = w1r[(size_t)(k - 128) * CH + n];
            ushort hh, ll; bsplit(v, hh, ll);
            w1T[i] = hh; w1T[128 * W1K + i] = ll;
        } else if (i < 128 * W1K + 128 * W2K) {
            int j2 = i - 128 * W1K;
            int n = j2 >> 7, k = j2 & 127;
            float v = 0.0f;
            if (n < COUT)                      v = w2l[(size_t)k * COUT + n];
            else if (n >= 64 && n < 64 + COUT) v = w2r[(size_t)k * COUT + (n - 64)];
            ushort hh, ll; bsplit(v, hh, ll);
            w2T[j2] = hh; w2T[128 * W2K + j2] = ll;
        } else {
            int j2 = i - (128 * W1K + 128 * W2K);
            if (j2 < 128) b2cat[j2] = (j2 >= 64 && j2 < 64 + COUT) ? b2l[j2 - 64] : 0.0f;
        }
    }
}

// P2a: per-bucket exclusive scan of lhist[*][b] across chunks (in-place);
// tot[b] = bucket total. 391 values = 2 chunks of 256 with carry.
__global__ __launch_bounds__(256) void scan_buckets(int* __restrict__ lhist,
        int* __restrict__ tot) {
    __shared__ int s[256];
    int b = blockIdx.x, t = threadIdx.x;
    int carry = 0;
    for (int c0 = 0; c0 < NCH; c0 += 256) {
        int c = c0 + t;
        int v = (c < NCH) ? lhist[(size_t)c * NBUK + b] : 0;
        s[t] = v;
        __syncthreads();
        for (int off = 1; off < 256; off <<= 1) {
            int a = s[t];
            int u = (t >= off) ? s[t - off] : 0;
            __syncthreads();
            s[t] = a + u;
            __syncthreads();
        }
        if (c < NCH) lhist[(size_t)c * NBUK + b] = carry + s[t] - v;
        carry += s[255];
        __syncthreads();
    }
    if (t == 0) tot[b] = carry;
}

// P2b: exclusive scan of tot[196] -> base[b]; base[NBUK] = total (= E).
__global__ __launch_bounds__(256) void scan_base(const int* __restrict__ tot,
        int* __restrict__ base) {
    __shared__ int s[256];
    int t = threadIdx.x;
    int v = (t < NBUK) ? tot[t] : 0;
    s[t] = v;
    __syncthreads();
    for (int off = 1; off < 256; off <<= 1) {
        int a = s[t];
        int u = (t >= off) ? s[t - off] : 0;
        __syncthreads();
        s[t] = a + u;
        __syncthreads();
    }
    if (t < NBUK) base[t] = s[t] - v;
    if (t == 0) base[NBUK] = s[255];
}

// P3: scatter edges into coarse-bucket-grouped ebuf. LDS cursors start at
// base[b]+lhist[c][b] (this block's deterministic range) — no global atomics.
// Packed: ebuf = src*256 + (dst&255) (src<2^16, local id 8 bits).
__global__ __launch_bounds__(256) void scatter_coarse(const int* __restrict__ src,
        const int* __restrict__ dst, const int* __restrict__ lhist,
        const int* __restrict__ base, int* __restrict__ ebuf) {
    __shared__ int cur[NBUK];
    int c = blockIdx.x, t = threadIdx.x;
    for (int i = t; i < NBUK; i += 256) cur[i] = base[i] + lhist[(size_t)c * NBUK + i];
    __syncthreads();
    int e0 = c * ECH + t * 8;
    if (e0 < E) {
        int4 d0 = *(const int4*)(dst + e0);
        int4 d1 = *(const int4*)(dst + e0 + 4);
        int4 s0 = *(const int4*)(src + e0);
        int4 s1 = *(const int4*)(src + e0 + 4);
        int dd[8] = {d0.x, d0.y, d0.z, d0.w, d1.x, d1.y, d1.z, d1.w};
        int ss[8] = {s0.x, s0.y, s0.z, s0.w, s1.x, s1.y, s1.z, s1.w};
        #pragma unroll
        for (int k = 0; k < 8; ++k) {
            int p = atomicAdd(&cur[dd[k] >> 8], 1);   // LDS atomic
            ebuf[p] = (ss[k] << 8) | (dd[k] & 255);
        }
    }
}

// P4: per-bucket fine CSR. Block b owns nodes [b*256, b*256+256) and edge
// segment [base[b], base[b+1]). LDS count -> LDS scan -> row_ptr; LDS-cursor
// scatter of col. All contended counters in LDS.
__global__ __launch_bounds__(256) void build_csr(const int* __restrict__ ebuf,
        const int* __restrict__ base, int* __restrict__ row_ptr,
        int* __restrict__ col) {
    __shared__ int cntL[256];
    __shared__ int s[256];
    int b = blockIdx.x, t = threadIdx.x;
    int segS = base[b], segE = base[b + 1];
    cntL[t] = 0;
    __syncthreads();
    for (int i = segS + t; i < segE; i += 256)
        atomicAdd(&cntL[ebuf[i] & 255], 1);
    __syncthreads();
    int v = cntL[t];
    s[t] = v;
    __syncthreads();
    for (int off = 1; off < 256; off <<= 1) {
        int a = s[t];
        int u = (t >= off) ? s[t - off] : 0;
        __syncthreads();
        s[t] = a + u;
        __syncthreads();
    }
    int start = segS + s[t] - v;          // exclusive prefix
    int node = b * 256 + t;
    if (node < N) row_ptr[node] = start;
    if (b == NBUK - 1 && t == 0) row_ptr[N] = E;
    cntL[t] = start;                      // reuse as cursor
    __syncthreads();
    for (int i = segS + t; i < segE; i += 256) {
        int v2 = ebuf[i];
        int p = atomicAdd(&cntL[v2 & 255], 1);
        col[p] = v2 >> 8;
    }
}

// ---------------------------------------------------------------------------
// gather1 (unchanged from R19 — 24 VGPR, high occupancy): fp16 source rows
// (200B). One node per wave; two 32-lane halves take even/odd edges, unroll-4
// per half; fp32 accumulation; cross-half __shfl_xor(..,32).
// Output: agg-section of a1x (halves 0..127; li>=25 lanes write the zero pad).
__global__ __launch_bounds__(256) void gather1_kernel(const __half* __restrict__ x16,
        const int* __restrict__ row_ptr, const int* __restrict__ col,
        __half* __restrict__ a1x) {
    int t = threadIdx.x;
    int n = blockIdx.x * 4 + (t >> 6);     // node per wave
    int l = t & 63, half = l >> 5, li = l & 31;
    int b = row_ptr[n], e = row_ptr[n + 1];
    float inv = 1.0f / (float)max(e - b, 1);
    const uint2* xb = (const uint2*)x16;   // row = 25 uint2 (4 halves each)
    bool act = li < 25;
    float4 s0 = make_float4(0.f, 0.f, 0.f, 0.f);
    float4 s1 = make_float4(0.f, 0.f, 0.f, 0.f);
    float4 s2 = make_float4(0.f, 0.f, 0.f, 0.f);
    float4 s3 = make_float4(0.f, 0.f, 0.f, 0.f);
    union { uint2 u; __half2 h[2]; } U0, U1, U2, U3;
    int j = b + half;
    for (; j + 6 < e; j += 8) {
        int c0 = col[j], c1 = col[j + 2], c2 = col[j + 4], c3 = col[j + 6];
        if (act) {
            U0.u = xb[(size_t)c0 * 25 + li];
            U1.u = xb[(size_t)c1 * 25 + li];
            U2.u = xb[(size_t)c2 * 25 + li];
            U3.u = xb[(size_t)c3 * 25 + li];
            float2 f0a = __half22float2(U0.h[0]), f0b = __half22float2(U0.h[1]);
            float2 f1a = __half22float2(U1.h[0]), f1b = __half22float2(U1.h[1]);
            float2 f2a = __half22float2(U2.h[0]), f2b = __half22float2(U2.h[1]);
            float2 f3a = __half22float2(U3.h[0]), f3b = __half22float2(U3.h[1]);
            s0.x += f0a.x; s0.y += f0a.y; s0.z += f0b.x; s0.w += f0b.y;
            s1.x += f1a.x; s1.y += f1a.y; s1.z += f1b.x; s1.w += f1b.y;
            s2.x += f2a.x; s2.y += f2a.y; s2.z += f2b.x; s2.w += f2b.y;
            s3.x += f3a.x; s3.y += f3a.y; s3.z += f3b.x; s3.w += f3b.y;
        }
    }
    for (; j < e; j += 2) {
        int c0 = col[j];
        if (act) {
            U0.u = xb[(size_t)c0 * 25 + li];
            float2 f0a = __half22float2(U0.h[0]), f0b = __half22float2(U0.h[1]);
            s0.x += f0a.x; s0.y += f0a.y; s0.z += f0b.x; s0.w += f0b.y;
        }
    }
    float4 s = make_float4(s0.x + s1.x + s2.x + s3.x,
                           s0.y + s1.y + s2.y + s3.y,
                           s0.z + s1.z + s2.z + s3.z,
                           s0.w + s1.w + s2.w + s3.w);
    s.x += __shfl_xor(s.x, 32, 64);
    s.y += __shfl_xor(s.y, 32, 64);
    s.z += __shfl_xor(s.z, 32, 64);
    s.w += __shfl_xor(s.w, 32, 64);
    if (half == 0) {                      // li>=25 lanes hold zeros -> pad
        __half2 p0 = __floats2half2_rn(s.x * inv, s.y * inv);
        __half2 p1 = __floats2half2_rn(s.z * inv, s.w * inv);
        union { __half2 h[2]; uint2 u; } P;
        P.h[0] = p0; P.h[1] = p1;
        ((uint2*)a1x)[(size_t)n * 64 + li] = P.u;
    }
}

// ---------------------------------------------------------------------------
// fused gemm (unchanged from R19): stage-1 is a single K=256 LDS-FREE
// direct-load GEMM — A-frags (16B = 8 fp16) read straight from a1x[N][256]
// (= [agg1|0|x|0], mirroring w1T's k-layout), bsplit in-register. No staging,
// no stage-1 barriers. h spills to LDS as bf16 hi/lo planes (stride 272B,
// ONE barrier), then stage-2 = h @ w2T^T. 3-term hh+hl+lh in fp32.
// LDS = 69632 B (H planes only) -> 2 blocks/CU.
__global__ __launch_bounds__(256) void fused_gemm(
        const __half* __restrict__ a1x,
        const ushort* __restrict__ w1T, const float* __restrict__ b1l,
        const ushort* __restrict__ w2T, const float* __restrict__ b2cat,
        __half* __restrict__ gsrc16, float* __restrict__ gself) {
    __shared__ __align__(16) uint lds_u[17408];   // 69632 B
    ushort* Hh = (ushort*)lds_u;                  // [128][HS]  (h hi)
    ushort* Hl = Hh + 128 * HS;                   // [128][HS]  (h lo)

    int t = threadIdx.x;
    int lane = t & 63;
    int wv = __builtin_amdgcn_readfirstlane(t >> 6);
    int nh = wv & 1, chh = wv >> 1;
    int l15 = lane & 15, lg = lane >> 4;
    int base = blockIdx.x * TN;

    const ushort* w1Th = w1T;
    const ushort* w1Tl = w1T + 128 * W1K;
    const ushort* w2Th = w2T;
    const ushort* w2Tl = w2T + 128 * W2K;

    f32x4 acc[4][4];
    #pragma unroll
    for (int nt = 0; nt < 4; ++nt) {
        float bv = b1l[chh * 64 + nt * 16 + l15];
        #pragma unroll
        for (int mt = 0; mt < 4; ++mt)
            acc[mt][nt] = f32x4{bv, bv, bv, bv};
    }

    // ---- stage 1: K=256, direct loads, no LDS, no barriers
    #pragma unroll 2
    for (int ks = 0; ks < 8; ++ks) {
        int k0 = ks * 32 + lg * 8;
        v8s ahf[4], alf[4];
        #pragma unroll
        for (int mt = 0; mt < 4; ++mt) {
            int row = base + nh * 64 + mt * 16 + l15;
            int rr = row < N ? row : N - 1;       // clamp loads; stores guarded
            uint4 v = *(const uint4*)(a1x + (size_t)rr * A1S + k0);
            unpack8(v, ahf[mt], alf[mt]);
        }
        #pragma unroll
        for (int nt = 0; nt < 4; ++nt) {
            int n = chh * 64 + nt * 16 + l15;
            v8s bhf = *(const v8s*)(w1Th + (size_t)n * W1K + k0);
            v8s blf = *(const v8s*)(w1Tl + (size_t)n * W1K + k0);
            #pragma unroll
            for (int mt = 0; mt < 4; ++mt) {
                acc[mt][nt] = __builtin_amdgcn_mfma_f32_16x16x32_bf16(
                    ahf[mt], bhf, acc[mt][nt], 0, 0, 0);
                acc[mt][nt] = __builtin_amdgcn_mfma_f32_16x16x32_bf16(
                    alf[mt], bhf, acc[mt][nt], 0, 0, 0);
                acc[mt][nt] = __builtin_amdgcn_mfma_f32_16x16x32_bf16(
                    ahf[mt], blf, acc[mt][nt], 0, 0, 0);
            }
        }
    }

    // ---- spill h tile to LDS as bf16 hi/lo planes
    #pragma unroll
    for (int mt = 0; mt < 4; ++mt) {
        #pragma unroll
        for (int nt = 0; nt < 4; ++nt) {
            int ch = chh * 64 + nt * 16 + l15;
            #pragma unroll
            for (int r = 0; r < 4; ++r) {
                int node = nh * 64 + mt * 16 + lg * 4 + r;
                ushort h, l; bsplit(acc[mt][nt][r], h, l);
                Hh[node * HS + ch] = h;
                Hl[node * HS + ch] = l;
            }
        }
    }
    __syncthreads();

    // ---- stage 2: [gsrc|gself] = h @ w2T^T (+ b2cat)
    bool skip = (chh == 1) && (base >= NOUT);
    if (!skip) {
        #pragma unroll
        for (int nt = 0; nt < 4; ++nt) {
            float bv = b2cat[chh * 64 + nt * 16 + l15];
            #pragma unroll
            for (int mt = 0; mt < 4; ++mt)
                acc[mt][nt] = f32x4{bv, bv, bv, bv};
        }
        #pragma unroll
        for (int ks = 0; ks < 4; ++ks) {          // K=128, 4 k-steps of 32
            v8s ahf[4], alf[4];
            #pragma unroll
            for (int mt = 0; mt < 4; ++mt) {
                int node = nh * 64 + mt * 16 + l15;
                int ko = ks * 32 + lg * 8;
                ahf[mt] = *(const v8s*)(Hh + node * HS + ko);
                alf[mt] = *(const v8s*)(Hl + node * HS + ko);
            }
            int kg = ks * 32 + lg * 8;
            #pragma unroll
            for (int nt = 0; nt < 4; ++nt) {
                int n = chh * 64 + nt * 16 + l15;
                v8s bhf = *(const v8s*)(w2Th + (size_t)n * W2K + kg);
                v8s blf = *(const v8s*)(w2Tl + (size_t)n * W2K + kg);
                #pragma unroll
                for (int mt = 0; mt < 4; ++mt) {
                    acc[mt][nt] = __builtin_amdgcn_mfma_f32_16x16x32_bf16(
                        ahf[mt], bhf, acc[mt][nt], 0, 0, 0);
                    acc[mt][nt] = __builtin_amdgcn_mfma_f32_16x16x32_bf16(
                        alf[mt], bhf, acc[mt][nt], 0, 0, 0);
                    acc[mt][nt] = __builtin_amdgcn_mfma_f32_16x16x32_bf16(
                        ahf[mt], blf, acc[mt][nt], 0, 0, 0);
                }
            }
        }
        int lim = chh ? NOUT : N;
        #pragma unroll
        for (int nt = 0; nt < 3; ++nt) {          // cols 0..47 only
            int colc = nt * 16 + l15;
            #pragma unroll
            for (int mt = 0; mt < 4; ++mt) {
                #pragma unroll
                for (int r = 0; r < 4; ++r) {
                    int node = base + nh * 64 + mt * 16 + lg * 4 + r;
                    if (node < lim) {
                        if (chh) gself[(size_t)node * CP + colc] = acc[mt][nt][r];
                        else gsrc16[(size_t)node * CP + colc] =
                                 __float2half(acc[mt][nt][r]);
                    }
                }
            }
        }
    }
}

// ---------------------------------------------------------------------------
// final: 4 nodes per 256-block (one per wave), unroll-4 fp16 gsrc gather.
// out nt store is safe: out is never read on-device.
__global__ __launch_bounds__(256) void final_kernel(const __half* __restrict__ gsrc16,
        const float* __restrict__ gself, const int* __restrict__ row_ptr,
        const int* __restrict__ col, float* __restrict__ out) {
    int t = threadIdx.x;
    int n = blockIdx.x * 4 + (t >> 6);
    int c = t & 63;
    int b = row_ptr[n], e = row_ptr[n + 1];
    float inv = 1.0f / (float)max(e - b, 1);
    float a0 = 0.f, a1 = 0.f, a2 = 0.f, a3 = 0.f;
    if (c < CP) {
        int j = b;
        for (; j + 3 < e; j += 4) {
            a0 += __half2float(gsrc16[(size_t)col[j]     * CP + c]);
            a1 += __half2float(gsrc16[(size_t)col[j + 1] * CP + c]);
            a2 += __half2float(gsrc16[(size_t)col[j + 2] * CP + c]);
            a3 += __half2float(gsrc16[(size_t)col[j + 3] * CP + c]);
        }
        for (; j < e; ++j) a0 += __half2float(gsrc16[(size_t)col[j] * CP + c]);
    }
    float val = (c < COUT)
        ? (((a0 + a1) + (a2 + a3)) * inv + gself[(size_t)n * CP + c]) : -INFINITY;
    float m = val;
    #pragma unroll
    for (int off = 32; off > 0; off >>= 1) m = fmaxf(m, __shfl_xor(m, off, 64));
    float ex = (c < COUT) ? expf(val - m) : 0.f;
    float ssum = ex;
    #pragma unroll
    for (int off = 32; off > 0; off >>= 1) ssum += __shfl_xor(ssum, off, 64);
    if (c < COUT)
        __builtin_nontemporal_store(val - m - logf(ssum),
                                    out + (size_t)n * COUT + c);
}

// ---------------------------------------------------------------------------
extern "C" void kernel_launch(void* const* d_in, const int* in_sizes, int n_in,
                              void* d_out, int out_size, void* d_ws, size_t ws_size,
                              hipStream_t stream) {
    const float* x   = (const float*)d_in[0];
    const int*   ei  = (const int*)d_in[1];   // [2, E]: row 0 = src, row 1 = dst
    const int*   src = ei;
    const int*   dst = ei + E;
    const float* w1l = (const float*)d_in[3];
    const float* b1l = (const float*)d_in[4];
    const float* w1r = (const float*)d_in[5];
    const float* w2l = (const float*)d_in[6];
    const float* b2l = (const float*)d_in[7];
    const float* w2r = (const float*)d_in[8];
    float* out = (float*)d_out;

    // ws: ints [row_ptr N+1 | lhist NCH*NBUK | tot NBUK | base NBUK+1
    //           | ebuf E | col E]
    // floats [gself NOUT*CP | b2cat 128]
    // halves [gsrc16 N*CP | x16 N*CIN | a1x N*256]
    // ushorts [w1T hi+lo 2*128*256 | w2T hi+lo 2*128*128]
    int* row_ptr = (int*)d_ws;
    int* lhist   = row_ptr + N + 1;
    int* tot     = lhist + (size_t)NCH * NBUK;
    int* base    = tot + NBUK;
    int* ebuf    = base + NBUK + 1;
    int* col     = ebuf + E;
    size_t intWords = (size_t)(N + 1) + (size_t)NCH * NBUK + NBUK + (NBUK + 1)
                      + E + E;
    intWords = (intWords + 3) & ~(size_t)3;
    float* gself  = (float*)d_ws + intWords;
    float* b2cat  = gself + (size_t)NOUT * CP;
    __half* gsrc16 = (__half*)(b2cat + 128);
    __half* x16    = gsrc16 + (size_t)N * CP;
    __half* a1x    = x16 + (size_t)N * CIN;       // 16B-aligned (counts %8==0)
    ushort* w1T   = (ushort*)(a1x + (size_t)N * A1S);
    ushort* w2T   = w1T + 2 * 128 * W1K;
    // total ws ~52.3 MB (< 58.6 MB proven available)

    pre_kernel    <<<NCH + CB + PB, 256, 0, stream>>>(dst, lhist, x, x16, a1x,
                                                      w1l, w1r, w2l, w2r, b2l,
                                                      w1T, w2T, b2cat);
    scan_buckets  <<<NBUK, 256, 0, stream>>>(lhist, tot);
    scan_base     <<<1, 256, 0, stream>>>(tot, base);
    scatter_coarse<<<NCH, 256, 0, stream>>>(src, dst, lhist, base, ebuf);
    build_csr     <<<NBUK, 256, 0, stream>>>(ebuf, base, row_ptr, col);
    gather1_kernel<<<N / 4, 256, 0, stream>>>(x16, row_ptr, col, a1x);
    fused_gemm    <<<NT, 256, 0, stream>>>(a1x, w1T, b1l, w2T, b2cat,
                                           gsrc16, gself);
    final_kernel  <<<NOUT / 4, 256, 0, stream>>>(gsrc16, gself, row_ptr, col, out);
}

// Round 12
// 202.169 us; speedup vs baseline: 1.2574x; 1.0063x over previous
//
#include <hip/hip_runtime.h>
#include <hip/hip_fp16.h>
#include <math.h>

// Problem constants (from reference setup_inputs)
constexpr int N    = 50000;   // nodes
constexpr int E    = 800000;  // edges
constexpr int CIN  = 100;     // input channels
constexpr int CH   = 128;     // hidden channels
constexpr int COUT = 47;      // output channels
constexpr int NOUT = 25000;   // original_size (rows emitted)
constexpr int CP   = 48;      // COUT padded (storage stride)
constexpr int TN   = 128;     // gemm tile nodes
constexpr int NT   = (N + TN - 1) / TN;      // 391 gemm blocks

// MFMA split-bf16 constants
constexpr int HS  = 136;  // h LDS row stride (halves) = 272 B (16B-aligned rows)
constexpr int W1K = 256;  // w1T row length (k): [agg1 0..99|0 | x 0..99|0]
constexpr int W2K = 128;  // w2T row length (k)
constexpr int A1S = 256;  // a1x row stride (halves) — mirrors w1T k-layout

// Atomic-free bucketed CSR constants
constexpr int NBUK = (N + 255) / 256;          // 196 coarse buckets (256 nodes)
constexpr int ECH  = 2048;                     // edges per chunk (256 thr x 8)
constexpr int NCH  = (E + ECH - 1) / ECH;      // 391 chunks

// pre_kernel block partition
constexpr int CB = (N * 32) / 256;             // 6250 convert blocks (32 u2/row)
constexpr int PB = 193;                        // prep blocks (49280 elems)

typedef float f32x4 __attribute__((ext_vector_type(4)));
typedef short v8s  __attribute__((ext_vector_type(8)));   // 8 bf16 (4 VGPRs)

// split fp32 -> truncated bf16 hi + bf16(residual) lo. For fp16 inputs the
// split is EXACT (11-bit mantissa = 8 hi + <=3 lo); dropping lo*lo in the
// 3-term MFMA leaves ~2^-16 rel error per product.
__device__ __forceinline__ void bsplit(float f, ushort& h, ushort& l) {
    uint u = __float_as_uint(f);
    h = (ushort)(u >> 16);
    float fh = __uint_as_float(u & 0xffff0000u);
    l = (ushort)(__float_as_uint(f - fh) >> 16);
}

// unpack 8 fp16 (one 16B vector) -> bf16 hi/lo MFMA fragments
__device__ __forceinline__ void unpack8(uint4 v, v8s& ah, v8s& al) {
    union { uint4 u; __half2 h[4]; } V; V.u = v;
    ushort hh[8], ll[8];
    #pragma unroll
    for (int p = 0; p < 4; ++p) {
        float2 f = __half22float2(V.h[p]);
        bsplit(f.x, hh[2 * p],     ll[2 * p]);
        bsplit(f.y, hh[2 * p + 1], ll[2 * p + 1]);
    }
    ah = v8s{(short)hh[0], (short)hh[1], (short)hh[2], (short)hh[3],
             (short)hh[4], (short)hh[5], (short)hh[6], (short)hh[7]};
    al = v8s{(short)ll[0], (short)ll[1], (short)ll[2], (short)ll[3],
             (short)ll[4], (short)ll[5], (short)ll[6], (short)ll[7]};
}

// ---------------------------------------------------------------------------
// pre_kernel: fused {coarse-hist (LDS) | convert_x | prep_w}. No global
// atomics (R20 null: device atomics are a fixed fabric ceiling).
__global__ __launch_bounds__(256) void pre_kernel(
        const int* __restrict__ dst, int* __restrict__ lhist,
        const float* __restrict__ x, __half* __restrict__ x16,
        __half* __restrict__ a1x,
        const float* __restrict__ w1l, const float* __restrict__ w1r,
        const float* __restrict__ w2l, const float* __restrict__ w2r,
        const float* __restrict__ b2l,
        ushort* __restrict__ w1T, ushort* __restrict__ w2T,
        float* __restrict__ b2cat) {
    __shared__ int h[NBUK];
    int bid = blockIdx.x, t = threadIdx.x;
    if (bid < NCH) {
        for (int i = t; i < NBUK; i += 256) h[i] = 0;
        __syncthreads();
        int e0 = bid * ECH + t * 8;        // E%8==0: group fully in or out
        if (e0 < E) {
            int4 d0 = *(const int4*)(dst + e0);
            int4 d1 = *(const int4*)(dst + e0 + 4);
            int dd[8] = {d0.x, d0.y, d0.z, d0.w, d1.x, d1.y, d1.z, d1.w};
            #pragma unroll
            for (int k = 0; k < 8; ++k) atomicAdd(&h[dd[k] >> 8], 1);
        }
        __syncthreads();
        for (int i = t; i < NBUK; i += 256) lhist[bid * NBUK + i] = h[i];
    } else if (bid < NCH + CB) {
        // x -> fp16: packed x16[N][100] (gather payload) AND the x-section of
        // a1x[N][256] halves 128..255 (cols >=100 zeroed).
        int j = (bid - NCH) * 256 + t;     // j over N*32 u2 slots
        int row = j >> 5, s = j & 31;
        uint2 u = make_uint2(0u, 0u);
        if (s < 25) {
            float4 v = ((const float4*)x)[row * 25 + s];
            __half2 h0 = __floats2half2_rn(v.x, v.y);
            __half2 h1 = __floats2half2_rn(v.z, v.w);
            union { __half2 h[2]; uint2 u; } U;
            U.h[0] = h0; U.h[1] = h1;
            u = U.u;
            ((uint2*)x16)[row * 25 + s] = u;
        }
        ((uint2*)a1x)[(size_t)row * 64 + 32 + s] = u;
    } else {
        // weight transpose + bf16 hi/lo split
        // w1T: [n<128][k<256]: k<100 -> w1l[k][n]; 128<=k<228 -> w1r[k-128][n]
        // w2T: [n<128][k<128]: n<47 -> w2l[k][n]; 64<=n<111 -> w2r[k][n-64]
        int i = (bid - NCH - CB) * 256 + t;
        if (i < 128 * W1K) {
            int n = i >> 8, k = i & 255;
            float v = 0.0f;
            if (k < 100)                    v = w1l[(size_t)k * CH + n];
            else if (k >= 128 && k < 228)   v = w1r[(size_t)(k - 128) * CH + n];
            ushort hh, ll; bsplit(v, hh, ll);
            w1T[i] = hh; w1T[128 * W1K + i] = ll;
        } else if (i < 128 * W1K + 128 * W2K) {
            int j2 = i - 128 * W1K;
            int n = j2 >> 7, k = j2 & 127;
            float v = 0.0f;
            if (n < COUT)                      v = w2l[(size_t)k * COUT + n];
            else if (n >= 64 && n < 64 + COUT) v = w2r[(size_t)k * COUT + (n - 64)];
            ushort hh, ll; bsplit(v, hh, ll);
            w2T[j2] = hh; w2T[128 * W2K + j2] = ll;
        } else {
            int j2 = i - (128 * W1K + 128 * W2K);
            if (j2 < 128) b2cat[j2] = (j2 >= 64 && j2 < 64 + COUT) ? b2l[j2 - 64] : 0.0f;
        }
    }
}

// P2: per-bucket exclusive scan of lhist[*][b] across chunks (in-place);
// tot[b] = bucket total.
__global__ __launch_bounds__(256) void scan_buckets(int* __restrict__ lhist,
        int* __restrict__ tot) {
    __shared__ int s[256];
    int b = blockIdx.x, t = threadIdx.x;
    int carry = 0;
    for (int c0 = 0; c0 < NCH; c0 += 256) {
        int c = c0 + t;
        int v = (c < NCH) ? lhist[(size_t)c * NBUK + b] : 0;
        s[t] = v;
        __syncthreads();
        for (int off = 1; off < 256; off <<= 1) {
            int a = s[t];
            int u = (t >= off) ? s[t - off] : 0;
            __syncthreads();
            s[t] = a + u;
            __syncthreads();
        }
        if (c < NCH) lhist[(size_t)c * NBUK + b] = carry + s[t] - v;
        carry += s[255];
        __syncthreads();
    }
    if (t == 0) tot[b] = carry;
}

// P3: scatter edges into coarse-bucket-grouped ebuf. R22: bucket base is
// recomputed per-block from tot (196-elem LDS scan, ~100cy) — scan_base
// kernel eliminated. LDS cursors start at base[b]+lhist[c][b].
// Packed: ebuf = src*256 + (dst&255) (src<2^16, local id 8 bits).
__global__ __launch_bounds__(256) void scatter_coarse(const int* __restrict__ src,
        const int* __restrict__ dst, const int* __restrict__ lhist,
        const int* __restrict__ tot, int* __restrict__ ebuf) {
    __shared__ int sb[256];
    __shared__ int cur[NBUK];
    int c = blockIdx.x, t = threadIdx.x;
    int v = (t < NBUK) ? tot[t] : 0;
    sb[t] = v;
    __syncthreads();
    for (int off = 1; off < 256; off <<= 1) {
        int a = sb[t];
        int u = (t >= off) ? sb[t - off] : 0;
        __syncthreads();
        sb[t] = a + u;
        __syncthreads();
    }
    if (t < NBUK) cur[t] = (sb[t] - v) + lhist[(size_t)c * NBUK + t];
    __syncthreads();
    int e0 = c * ECH + t * 8;
    if (e0 < E) {
        int4 d0 = *(const int4*)(dst + e0);
        int4 d1 = *(const int4*)(dst + e0 + 4);
        int4 s0 = *(const int4*)(src + e0);
        int4 s1 = *(const int4*)(src + e0 + 4);
        int dd[8] = {d0.x, d0.y, d0.z, d0.w, d1.x, d1.y, d1.z, d1.w};
        int ss[8] = {s0.x, s0.y, s0.z, s0.w, s1.x, s1.y, s1.z, s1.w};
        #pragma unroll
        for (int k = 0; k < 8; ++k) {
            int p = atomicAdd(&cur[dd[k] >> 8], 1);   // LDS atomic
            ebuf[p] = (ss[k] << 8) | (dd[k] & 255);
        }
    }
}

// P4: per-bucket fine CSR. Block b owns nodes [b*256, b*256+256) and its
// edge segment. Bucket base recomputed from tot (R22). LDS count -> scan ->
// row_ptr; LDS-cursor scatter of col.
__global__ __launch_bounds__(256) void build_csr(const int* __restrict__ ebuf,
        const int* __restrict__ tot, int* __restrict__ row_ptr,
        int* __restrict__ col) {
    __shared__ int sb[256];
    __shared__ int cntL[256];
    __shared__ int s[256];
    int b = blockIdx.x, t = threadIdx.x;
    int v0 = (t < NBUK) ? tot[t] : 0;
    sb[t] = v0;
    __syncthreads();
    for (int off = 1; off < 256; off <<= 1) {
        int a = sb[t];
        int u = (t >= off) ? sb[t - off] : 0;
        __syncthreads();
        sb[t] = a + u;
        __syncthreads();
    }
    int tb = tot[b];                      // block-uniform (L2-hot)
    int segE = sb[b];                     // inclusive prefix = base[b]+tot[b]
    int segS = segE - tb;
    cntL[t] = 0;
    __syncthreads();
    for (int i = segS + t; i < segE; i += 256)
        atomicAdd(&cntL[ebuf[i] & 255], 1);
    __syncthreads();
    int v = cntL[t];
    s[t] = v;
    __syncthreads();
    for (int off = 1; off < 256; off <<= 1) {
        int a = s[t];
        int u = (t >= off) ? s[t - off] : 0;
        __syncthreads();
        s[t] = a + u;
        __syncthreads();
    }
    int start = segS + s[t] - v;          // exclusive prefix
    int node = b * 256 + t;
    if (node < N) row_ptr[node] = start;
    if (b == NBUK - 1 && t == 0) row_ptr[N] = E;
    cntL[t] = start;                      // reuse as cursor
    __syncthreads();
    for (int i = segS + t; i < segE; i += 256) {
        int v2 = ebuf[i];
        int p = atomicAdd(&cntL[v2 & 255], 1);
        col[p] = v2 >> 8;
    }
}

// ---------------------------------------------------------------------------
// gather1 (unchanged — 24 VGPR, high occupancy): fp16 source rows (200B).
// One node per wave; two 32-lane halves take even/odd edges, unroll-4 per
// half; fp32 accumulation; cross-half __shfl_xor(..,32).
// Output: agg-section of a1x (halves 0..127; li>=25 lanes write the zero pad).
__global__ __launch_bounds__(256) void gather1_kernel(const __half* __restrict__ x16,
        const int* __restrict__ row_ptr, const int* __restrict__ col,
        __half* __restrict__ a1x) {
    int t = threadIdx.x;
    int n = blockIdx.x * 4 + (t >> 6);     // node per wave
    int l = t & 63, half = l >> 5, li = l & 31;
    int b = row_ptr[n], e = row_ptr[n + 1];
    float inv = 1.0f / (float)max(e - b, 1);
    const uint2* xb = (const uint2*)x16;   // row = 25 uint2 (4 halves each)
    bool act = li < 25;
    float4 s0 = make_float4(0.f, 0.f, 0.f, 0.f);
    float4 s1 = make_float4(0.f, 0.f, 0.f, 0.f);
    float4 s2 = make_float4(0.f, 0.f, 0.f, 0.f);
    float4 s3 = make_float4(0.f, 0.f, 0.f, 0.f);
    union { uint2 u; __half2 h[2]; } U0, U1, U2, U3;
    int j = b + half;
    for (; j + 6 < e; j += 8) {
        int c0 = col[j], c1 = col[j + 2], c2 = col[j + 4], c3 = col[j + 6];
        if (act) {
            U0.u = xb[(size_t)c0 * 25 + li];
            U1.u = xb[(size_t)c1 * 25 + li];
            U2.u = xb[(size_t)c2 * 25 + li];
            U3.u = xb[(size_t)c3 * 25 + li];
            float2 f0a = __half22float2(U0.h[0]), f0b = __half22float2(U0.h[1]);
            float2 f1a = __half22float2(U1.h[0]), f1b = __half22float2(U1.h[1]);
            float2 f2a = __half22float2(U2.h[0]), f2b = __half22float2(U2.h[1]);
            float2 f3a = __half22float2(U3.h[0]), f3b = __half22float2(U3.h[1]);
            s0.x += f0a.x; s0.y += f0a.y; s0.z += f0b.x; s0.w += f0b.y;
            s1.x += f1a.x; s1.y += f1a.y; s1.z += f1b.x; s1.w += f1b.y;
            s2.x += f2a.x; s2.y += f2a.y; s2.z += f2b.x; s2.w += f2b.y;
            s3.x += f3a.x; s3.y += f3a.y; s3.z += f3b.x; s3.w += f3b.y;
        }
    }
    for (; j < e; j += 2) {
        int c0 = col[j];
        if (act) {
            U0.u = xb[(size_t)c0 * 25 + li];
            float2 f0a = __half22float2(U0.h[0]), f0b = __half22float2(U0.h[1]);
            s0.x += f0a.x; s0.y += f0a.y; s0.z += f0b.x; s0.w += f0b.y;
        }
    }
    float4 s = make_float4(s0.x + s1.x + s2.x + s3.x,
                           s0.y + s1.y + s2.y + s3.y,
                           s0.z + s1.z + s2.z + s3.z,
                           s0.w + s1.w + s2.w + s3.w);
    s.x += __shfl_xor(s.x, 32, 64);
    s.y += __shfl_xor(s.y, 32, 64);
    s.z += __shfl_xor(s.z, 32, 64);
    s.w += __shfl_xor(s.w, 32, 64);
    if (half == 0) {                      // li>=25 lanes hold zeros -> pad
        __half2 p0 = __floats2half2_rn(s.x * inv, s.y * inv);
        __half2 p1 = __floats2half2_rn(s.z * inv, s.w * inv);
        union { __half2 h[2]; uint2 u; } P;
        P.h[0] = p0; P.h[1] = p1;
        ((uint2*)a1x)[(size_t)n * 64 + li] = P.u;
    }
}

// ---------------------------------------------------------------------------
// fused gemm. R22: h round-trips LDS as ONE fp16 plane (34,816 B — was two
// bf16 hi/lo planes at 69,632) -> LDS allows 4 blocks/CU (VGPR may cap at 3).
// fp16->bf16 hi/lo on read is exact; only h's fp16 rounding (~2^-12) added,
// same scale as gsrc16 which already passed. Stage-1 unchanged: single K=256
// LDS-free direct-load GEMM from a1x, bsplit in-register, no barriers.
__global__ __launch_bounds__(256) void fused_gemm(
        const __half* __restrict__ a1x,
        const ushort* __restrict__ w1T, const float* __restrict__ b1l,
        const ushort* __restrict__ w2T, const float* __restrict__ b2cat,
        __half* __restrict__ gsrc16, float* __restrict__ gself) {
    __shared__ __align__(16) uint lds_u[8704];    // 34,816 B
    __half* H16 = (__half*)lds_u;                 // [128][HS] fp16 h plane

    int t = threadIdx.x;
    int lane = t & 63;
    int wv = __builtin_amdgcn_readfirstlane(t >> 6);
    int nh = wv & 1, chh = wv >> 1;
    int l15 = lane & 15, lg = lane >> 4;
    int base = blockIdx.x * TN;

    const ushort* w1Th = w1T;
    const ushort* w1Tl = w1T + 128 * W1K;
    const ushort* w2Th = w2T;
    const ushort* w2Tl = w2T + 128 * W2K;

    f32x4 acc[4][4];
    #pragma unroll
    for (int nt = 0; nt < 4; ++nt) {
        float bv = b1l[chh * 64 + nt * 16 + l15];
        #pragma unroll
        for (int mt = 0; mt < 4; ++mt)
            acc[mt][nt] = f32x4{bv, bv, bv, bv};
    }

    // ---- stage 1: K=256, direct loads, no LDS, no barriers
    #pragma unroll 2
    for (int ks = 0; ks < 8; ++ks) {
        int k0 = ks * 32 + lg * 8;
        v8s ahf[4], alf[4];
        #pragma unroll
        for (int mt = 0; mt < 4; ++mt) {
            int row = base + nh * 64 + mt * 16 + l15;
            int rr = row < N ? row : N - 1;       // clamp loads; stores guarded
            uint4 v = *(const uint4*)(a1x + (size_t)rr * A1S + k0);
            unpack8(v, ahf[mt], alf[mt]);
        }
        #pragma unroll
        for (int nt = 0; nt < 4; ++nt) {
            int n = chh * 64 + nt * 16 + l15;
            v8s bhf = *(const v8s*)(w1Th + (size_t)n * W1K + k0);
            v8s blf = *(const v8s*)(w1Tl + (size_t)n * W1K + k0);
            #pragma unroll
            for (int mt = 0; mt < 4; ++mt) {
                acc[mt][nt] = __builtin_amdgcn_mfma_f32_16x16x32_bf16(
                    ahf[mt], bhf, acc[mt][nt], 0, 0, 0);
                acc[mt][nt] = __builtin_amdgcn_mfma_f32_16x16x32_bf16(
                    alf[mt], bhf, acc[mt][nt], 0, 0, 0);
                acc[mt][nt] = __builtin_amdgcn_mfma_f32_16x16x32_bf16(
                    ahf[mt], blf, acc[mt][nt], 0, 0, 0);
            }
        }
    }

    // ---- spill h tile to LDS as one fp16 plane
    #pragma unroll
    for (int mt = 0; mt < 4; ++mt) {
        #pragma unroll
        for (int nt = 0; nt < 4; ++nt) {
            int ch = chh * 64 + nt * 16 + l15;
            #pragma unroll
            for (int r = 0; r < 4; ++r) {
                int node = nh * 64 + mt * 16 + lg * 4 + r;
                H16[node * HS + ch] = __float2half(acc[mt][nt][r]);
            }
        }
    }
    __syncthreads();

    // ---- stage 2: [gsrc|gself] = h @ w2T^T (+ b2cat)
    bool skip = (chh == 1) && (base >= NOUT);
    if (!skip) {
        #pragma unroll
        for (int nt = 0; nt < 4; ++nt) {
            float bv = b2cat[chh * 64 + nt * 16 + l15];
            #pragma unroll
            for (int mt = 0; mt < 4; ++mt)
                acc[mt][nt] = f32x4{bv, bv, bv, bv};
        }
        #pragma unroll
        for (int ks = 0; ks < 4; ++ks) {          // K=128, 4 k-steps of 32
            v8s ahf[4], alf[4];
            #pragma unroll
            for (int mt = 0; mt < 4; ++mt) {
                int node = nh * 64 + mt * 16 + l15;
                int ko = ks * 32 + lg * 8;
                uint4 v = *(const uint4*)(H16 + node * HS + ko);
                unpack8(v, ahf[mt], alf[mt]);
            }
            int kg = ks * 32 + lg * 8;
            #pragma unroll
            for (int nt = 0; nt < 4; ++nt) {
                int n = chh * 64 + nt * 16 + l15;
                v8s bhf = *(const v8s*)(w2Th + (size_t)n * W2K + kg);
                v8s blf = *(const v8s*)(w2Tl + (size_t)n * W2K + kg);
                #pragma unroll
                for (int mt = 0; mt < 4; ++mt) {
                    acc[mt][nt] = __builtin_amdgcn_mfma_f32_16x16x32_bf16(
                        ahf[mt], bhf, acc[mt][nt], 0, 0, 0);
                    acc[mt][nt] = __builtin_amdgcn_mfma_f32_16x16x32_bf16(
                        alf[mt], bhf, acc[mt][nt], 0, 0, 0);
                    acc[mt][nt] = __builtin_amdgcn_mfma_f32_16x16x32_bf16(
                        ahf[mt], blf, acc[mt][nt], 0, 0, 0);
                }
            }
        }
        int lim = chh ? NOUT : N;
        #pragma unroll
        for (int nt = 0; nt < 3; ++nt) {          // cols 0..47 only
            int colc = nt * 16 + l15;
            #pragma unroll
            for (int mt = 0; mt < 4; ++mt) {
                #pragma unroll
                for (int r = 0; r < 4; ++r) {
                    int node = base + nh * 64 + mt * 16 + lg * 4 + r;
                    if (node < lim) {
                        if (chh) gself[(size_t)node * CP + colc] = acc[mt][nt][r];
                        else gsrc16[(size_t)node * CP + colc] =
                                 __float2half(acc[mt][nt][r]);
                    }
                }
            }
        }
    }
}

// ---------------------------------------------------------------------------
// final: 4 nodes per 256-block (one per wave), unroll-4 fp16 gsrc gather.
// out nt store is safe: out is never read on-device.
__global__ __launch_bounds__(256) void final_kernel(const __half* __restrict__ gsrc16,
        const float* __restrict__ gself, const int* __restrict__ row_ptr,
        const int* __restrict__ col, float* __restrict__ out) {
    int t = threadIdx.x;
    int n = blockIdx.x * 4 + (t >> 6);
    int c = t & 63;
    int b = row_ptr[n], e = row_ptr[n + 1];
    float inv = 1.0f / (float)max(e - b, 1);
    float a0 = 0.f, a1 = 0.f, a2 = 0.f, a3 = 0.f;
    if (c < CP) {
        int j = b;
        for (; j + 3 < e; j += 4) {
            a0 += __half2float(gsrc16[(size_t)col[j]     * CP + c]);
            a1 += __half2float(gsrc16[(size_t)col[j + 1] * CP + c]);
            a2 += __half2float(gsrc16[(size_t)col[j + 2] * CP + c]);
            a3 += __half2float(gsrc16[(size_t)col[j + 3] * CP + c]);
        }
        for (; j < e; ++j) a0 += __half2float(gsrc16[(size_t)col[j] * CP + c]);
    }
    float val = (c < COUT)
        ? (((a0 + a1) + (a2 + a3)) * inv + gself[(size_t)n * CP + c]) : -INFINITY;
    float m = val;
    #pragma unroll
    for (int off = 32; off > 0; off >>= 1) m = fmaxf(m, __shfl_xor(m, off, 64));
    float ex = (c < COUT) ? expf(val - m) : 0.f;
    float ssum = ex;
    #pragma unroll
    for (int off = 32; off > 0; off >>= 1) ssum += __shfl_xor(ssum, off, 64);
    if (c < COUT)
        __builtin_nontemporal_store(val - m - logf(ssum),
                                    out + (size_t)n * COUT + c);
}

// ---------------------------------------------------------------------------
extern "C" void kernel_launch(void* const* d_in, const int* in_sizes, int n_in,
                              void* d_out, int out_size, void* d_ws, size_t ws_size,
                              hipStream_t stream) {
    const float* x   = (const float*)d_in[0];
    const int*   ei  = (const int*)d_in[1];   // [2, E]: row 0 = src, row 1 = dst
    const int*   src = ei;
    const int*   dst = ei + E;
    const float* w1l = (const float*)d_in[3];
    const float* b1l = (const float*)d_in[4];
    const float* w1r = (const float*)d_in[5];
    const float* w2l = (const float*)d_in[6];
    const float* b2l = (const float*)d_in[7];
    const float* w2r = (const float*)d_in[8];
    float* out = (float*)d_out;

    // ws: ints [row_ptr N+1 | lhist NCH*NBUK | tot NBUK | ebuf E | col E]
    // floats [gself NOUT*CP | b2cat 128]
    // halves [gsrc16 N*CP | x16 N*CIN | a1x N*256]
    // ushorts [w1T hi+lo 2*128*256 | w2T hi+lo 2*128*128]
    int* row_ptr = (int*)d_ws;
    int* lhist   = row_ptr + N + 1;
    int* tot     = lhist + (size_t)NCH * NBUK;
    int* ebuf    = tot + NBUK;
    int* col     = ebuf + E;
    size_t intWords = (size_t)(N + 1) + (size_t)NCH * NBUK + NBUK + E + E;
    intWords = (intWords + 3) & ~(size_t)3;
    float* gself  = (float*)d_ws + intWords;
    float* b2cat  = gself + (size_t)NOUT * CP;
    __half* gsrc16 = (__half*)(b2cat + 128);
    __half* x16    = gsrc16 + (size_t)N * CP;
    __half* a1x    = x16 + (size_t)N * CIN;       // 16B-aligned (counts %8==0)
    ushort* w1T   = (ushort*)(a1x + (size_t)N * A1S);
    ushort* w2T   = w1T + 2 * 128 * W1K;
    // total ws ~52.3 MB (< 58.6 MB proven available)

    pre_kernel    <<<NCH + CB + PB, 256, 0, stream>>>(dst, lhist, x, x16, a1x,
                                                      w1l, w1r, w2l, w2r, b2l,
                                                      w1T, w2T, b2cat);
    scan_buckets  <<<NBUK, 256, 0, stream>>>(lhist, tot);
    scatter_coarse<<<NCH, 256, 0, stream>>>(src, dst, lhist, tot, ebuf);
    build_csr     <<<NBUK, 256, 0, stream>>>(ebuf, tot, row_ptr, col);
    gather1_kernel<<<N / 4, 256, 0, stream>>>(x16, row_ptr, col, a1x);
    fused_gemm    <<<NT, 256, 0, stream>>>(a1x, w1T, b1l, w2T, b2cat,
                                           gsrc16, gself);
    final_kernel  <<<NOUT / 4, 256, 0, stream>>>(gsrc16, gself, row_ptr, col, out);
}